// Round 14
// baseline (224.876 us; speedup 1.0000x reference)
//
#include <hip/hip_runtime.h>
#include <hip/hip_bf16.h>
#include <cstddef>

#define NN 50000
#define NE 1000000
#define F  128
#define KH 4
#define NEG 0.01f
#define EPSF 1e-8f
#define CAP 64
#define NBIN 196                       // bin = src >> 8  (50000>>8 = 195 max)
#define BINCAP 8192                    // mean 5102/bin, +43 sigma headroom
#define EPB 8192                       // edges per chunk (two-pass)
#define SUBS 2                         // bin subsets per chunk
#define NCH ((NE + EPB - 1) / EPB)     // 123 chunks
#define NB1 (NCH * SUBS)               // 246 edge blocks
#define NBW 256                        // wt transpose blocks
#define NBP 2048                       // prep blocks (fused, non-temporal)
#define STR (NBP * 4)                  // prep wave stride = 8192
#define MXSTR 32                       // mxs padding: 32 floats = 128 B/line
#define TSTR 32                        // binTail padding: 32 ints = 128 B/line

typedef short bf16x8 __attribute__((ext_vector_type(8)));
typedef float f32x4 __attribute__((ext_vector_type(4)));
typedef unsigned long long u64;

__device__ inline ushort f2bf(float f) {
    __hip_bfloat16 b = __float2bfloat16(f);
    return *reinterpret_cast<ushort*>(&b);
}
__device__ inline unsigned int packbf(float xl, float xh) {
    return (unsigned int)f2bf(xl) | ((unsigned int)f2bf(xh) << 16);
}
__device__ inline float lk(float v) { return (v >= 0.f) ? v : NEG * v; }

// ---------------- K0: vv precompute + zero binTail/mxs (1 block) ----------------
__global__ __launch_bounds__(256) void vv_kernel(const float* __restrict__ W,
                                                 const float* __restrict__ a,
                                                 float* __restrict__ vvg,
                                                 int* __restrict__ binTail,
                                                 float* __restrict__ mxs) {
    int tid = threadIdx.x;
    for (int i = tid; i < NBIN * TSTR; i += 256) binTail[i] = 0;
    for (int i = tid; i < 8 * MXSTR; i += 256) mxs[i] = 0.f;
    int j0 = tid * 4;
#pragma unroll
    for (int ii = 0; ii < 4; ii++) {
        int j = j0 + ii;                      // 0..1023
        int side = j >> 9;
        int k = (j >> 7) & 3;
        int dd = j & 127;
        const float4* Wr = (const float4*)(W + (size_t)k * F * F + (size_t)dd * F);
        const float4* ar = (const float4*)(a + (size_t)k * 2 * F + side * F);
        float acc = 0.f;
#pragma unroll 8
        for (int o = 0; o < F / 4; o++) {
            float4 wv = Wr[o], av = ar[o];
            acc += wv.x * av.x + wv.y * av.y + wv.z * av.z + wv.w * av.w;
        }
        vvg[j] = acc;
    }
}

// ---------------- K1: edge binning || prep (non-temporal) || W->bf16^T ----------------
// prep is L2-invisible (nt loads of x, nt stores of xb2) so bin's binbuf
// scatter lines can merge in L2 undisturbed (R11 failure mechanism).
__global__ __launch_bounds__(256, 4) void bin_prep_kernel(const int* __restrict__ adj,
                                                          int* __restrict__ binTail,
                                                          unsigned int* __restrict__ binbuf,
                                                          const float* __restrict__ W,
                                                          ushort* __restrict__ wt,
                                                          const float* __restrict__ vvg,
                                                          const float* __restrict__ x,
                                                          unsigned int* __restrict__ xb2,
                                                          float* __restrict__ ssrc4,
                                                          float* __restrict__ sdst4,
                                                          int* __restrict__ mxsi) {
    int b = blockIdx.x;
    int tid = threadIdx.x;
    __shared__ __align__(16) int shmem[1024];          // 4 KB: hist (bin) / vv (prep)
    __shared__ float bmax_s[4][8];

    if (b < NB1) {
        // chunk of 8192 edges; this block handles bins with (bin&1)==sub.
        // pass 1: histogram (ILP8); reserve (padded atomics); pass 2: scatter (~168 B runs)
        int* hist = shmem;
        int chunk = b >> 1, sub = b & (SUBS - 1);
        int base = chunk * EPB;
        int nloc = min(EPB, NE - base);
        for (int i = tid; i < NBIN; i += 256) hist[i] = 0;
        __syncthreads();
        for (int off0 = 0; off0 < EPB; off0 += 256 * 8) {
            int sv[8]; bool va[8];
#pragma unroll
            for (int u = 0; u < 8; u++) {
                int off = off0 + u * 256 + tid;
                va[u] = off < nloc;
                sv[u] = adj[base + (va[u] ? off : 0)];
            }
#pragma unroll
            for (int u = 0; u < 8; u++) {
                int bn = ((unsigned int)sv[u]) >> 8;
                if (va[u] && (bn & (SUBS - 1)) == sub) atomicAdd(&hist[bn], 1);
            }
        }
        __syncthreads();
        for (int i = tid; i < NBIN; i += 256) {
            if ((i & (SUBS - 1)) == sub) {
                int c = hist[i];
                hist[i] = atomicAdd(&binTail[i * TSTR], c);   // hist := global base offset
            }
        }
        __syncthreads();
        for (int off0 = 0; off0 < EPB; off0 += 256 * 8) {
            int sv[8], dv[8]; bool va[8];
#pragma unroll
            for (int u = 0; u < 8; u++) {
                int off = off0 + u * 256 + tid;
                va[u] = off < nloc;
                int e = base + (va[u] ? off : 0);
                sv[u] = adj[e];
                dv[u] = adj[NE + e];
            }
#pragma unroll
            for (int u = 0; u < 8; u++) {
                unsigned int s = (unsigned int)sv[u];
                int bn = s >> 8;
                if (va[u] && (bn & (SUBS - 1)) == sub) {
                    int p = atomicAdd(&hist[bn], 1);
                    if (p < BINCAP) binbuf[(size_t)bn * BINCAP + p] = (s << 16) | (unsigned int)dv[u];
                }
            }
        }
        return;
    }
    if (b >= NB1 + NBP) {
        // ---- W -> bf16 transposed: wt[k][o][d] ----
        int i = (b - NB1 - NBP) * 256 + tid;     // covers KH*F*F = 65536
        int k = i >> 14;
        int dd = (i >> 7) & 127;
        int o = i & 127;
        wt[((size_t)k * F + o) * F + dd] = f2bf(W[i]);
        return;
    }

    // ---- prep (non-temporal: invisible to L2) ----
    float* vvf = (float*)shmem;                        // 8*128 floats
    ((float4*)vvf)[tid] = ((const float4*)vvg)[tid];   // 1024 floats
    __syncthreads();

    int wv = tid >> 6, lane = tid & 63;
    int gw = (b - NB1) * 4 + wv;                       // 0..8191
    const u64* x8 = (const u64*)x;
    float2 vs[4], vd[4];
#pragma unroll
    for (int k = 0; k < 4; k++) {
        vs[k] = *(const float2*)&vvf[k * F + 2 * lane];
        vd[k] = *(const float2*)&vvf[(4 + k) * F + 2 * lane];
    }
    int l1 = lane & 1, l2 = lane & 2, l4 = lane & 4;
    int j = 4 * l1 + l2 + (l4 >> 2);           // value index this lane ends with
    float* sp = (j < 4) ? (ssrc4 + j) : (sdst4 + (j - 4));
    float mxv = 0.f;

    for (int n = gw; n < NN; n += 2 * STR) {
        int nb = n + STR;
        bool vb = nb < NN;
        union { u64 u; float2 f; } cva, cvb;
        cva.u = __builtin_nontemporal_load(x8 + (size_t)n * 64 + lane);
        cvb.u = vb ? __builtin_nontemporal_load(x8 + (size_t)nb * 64 + lane) : 0ull;
        float2 xa = cva.f, xbv = cvb.f;
        __builtin_nontemporal_store(packbf(xa.x, xa.y), &xb2[(size_t)n * 64 + lane]);
        if (vb) __builtin_nontemporal_store(packbf(xbv.x, xbv.y), &xb2[(size_t)nb * 64 + lane]);
        float s[8], q[8];
#pragma unroll
        for (int k = 0; k < 4; k++) {
            s[k]     = xa.x * vs[k].x + xa.y * vs[k].y;
            s[4 + k] = xa.x * vd[k].x + xa.y * vd[k].y;
            q[k]     = xbv.x * vs[k].x + xbv.y * vs[k].y;
            q[4 + k] = xbv.x * vd[k].x + xbv.y * vd[k].y;
        }
        // two interleaved fold reduces: 8 values x 64 lanes -> per-lane totals
        float tA[4], tB[4];
#pragma unroll
        for (int i = 0; i < 4; i++) {
            float mA = l1 ? s[4 + i] : s[i];
            float oA = __shfl_xor(l1 ? s[i] : s[4 + i], 1);
            tA[i] = mA + oA;
            float mB = l1 ? q[4 + i] : q[i];
            float oB = __shfl_xor(l1 ? q[i] : q[4 + i], 1);
            tB[i] = mB + oB;
        }
        float uA[2], uB[2];
#pragma unroll
        for (int i = 0; i < 2; i++) {
            float mA = l2 ? tA[2 + i] : tA[i];
            float oA = __shfl_xor(l2 ? tA[i] : tA[2 + i], 2);
            uA[i] = mA + oA;
            float mB = l2 ? tB[2 + i] : tB[i];
            float oB = __shfl_xor(l2 ? tB[i] : tB[2 + i], 2);
            uB[i] = mB + oB;
        }
        float vA, vB;
        {
            float mA = l4 ? uA[1] : uA[0];
            float oA = __shfl_xor(l4 ? uA[0] : uA[1], 4);
            vA = mA + oA;
            float mB = l4 ? uB[1] : uB[0];
            float oB = __shfl_xor(l4 ? uB[0] : uB[1], 4);
            vB = mB + oB;
        }
        vA += __shfl_xor(vA, 8);  vB += __shfl_xor(vB, 8);
        vA += __shfl_xor(vA, 16); vB += __shfl_xor(vB, 16);
        vA += __shfl_xor(vA, 32); vB += __shfl_xor(vB, 32);
        if (lane < 8) {
            sp[(size_t)n * 4] = vA;
            if (vb) sp[(size_t)nb * 4] = vB;
        }
        mxv = fmaxf(mxv, fmaxf(vA, vB));   // vB == 0 when invalid: safe (max init 0)
    }
    // block-level max reduce -> 8 atomics per BLOCK, each on its own 128B line
    if (lane < 8) bmax_s[wv][j] = mxv;
    __syncthreads();
    if (tid < 8) {
        float m = fmaxf(fmaxf(bmax_s[0][tid], bmax_s[1][tid]),
                        fmaxf(bmax_s[2][tid], bmax_s[3][tid]));
        atomicMax(&mxsi[tid * MXSTR], __float_as_int(m));   // maxima >= 0: bit-monotone
    }
}

// ---------------- K2: bucket build only (196 blocks, two-pass, 2KB LDS) ----------------
__global__ __launch_bounds__(256) void build_kernel(const int* __restrict__ binTail,
                                                    const unsigned int* __restrict__ binbuf,
                                                    int* __restrict__ cnt,
                                                    ushort* __restrict__ bucket16) {
    int tid = threadIdx.x;
    __shared__ int lcnt[256];
    __shared__ int lpos[256];
    int b = blockIdx.x;
    lcnt[tid] = 0;
    lpos[tid] = 0;
    __syncthreads();
    int tail = min(binTail[b * TSTR], BINCAP);
    const unsigned int* bb = binbuf + (size_t)b * BINCAP;
    for (int i = tid; i < tail; i += 256) {
        unsigned int pk = bb[i];
        atomicAdd(&lcnt[(pk >> 16) & 255], 1);
    }
    __syncthreads();
    int n0 = b << 8;
    cnt[n0 + tid] = lcnt[tid];
    for (int i = tid; i < tail; i += 256) {
        unsigned int pk = bb[i];                   // L2-hit re-read
        int sl = (pk >> 16) & 255;
        int p = atomicAdd(&lpos[sl], 1);
        if (p < CAP) bucket16[(size_t)(n0 + sl) * CAP + p] = (ushort)(pk & 0xffffu);
    }
}

// ---------------- aggregate: wave-per-node, SALU-addressed gather, hoisted denominators ----------------
// z[n][k*F + o] = (e_k/(den_k+eps)) * (w_self*x[n] + sum_j w_jk * x[dst_j])   [bf16]
__global__ __launch_bounds__(256) void aggregate_kernel(const unsigned int* __restrict__ xb2,
                                                        const float* __restrict__ ssrc4,
                                                        const float* __restrict__ sdst4,
                                                        const float* __restrict__ mxs,
                                                        const int* __restrict__ cnt,
                                                        const ushort* __restrict__ bucket16,
                                                        const float* __restrict__ ew,
                                                        unsigned int* __restrict__ z2) {
    int wv = threadIdx.x >> 6, lane = threadIdx.x & 63;
    int n = blockIdx.x * 4 + wv;
    if (n >= NN) return;                       // wave-uniform; no barriers below

    __shared__ int dsh[4][64];
    __shared__ __align__(16) float wsh[4][64][4];

    float m0 = lk(mxs[0 * MXSTR] + mxs[4 * MXSTR]);
    float m1 = lk(mxs[1 * MXSTR] + mxs[5 * MXSTR]);
    float m2 = lk(mxs[2 * MXSTR] + mxs[6 * MXSTR]);
    float m3 = lk(mxs[3 * MXSTR] + mxs[7 * MXSTR]);
    float4 ss  = *(const float4*)&ssrc4[(size_t)n * 4];
    float4 sdn = *(const float4*)&sdst4[(size_t)n * 4];
    float w0s = __expf(lk(ss.x + sdn.x) - m0);
    float w1s = __expf(lk(ss.y + sdn.y) - m1);
    float w2s = __expf(lk(ss.z + sdn.z) - m2);
    float w3s = __expf(lk(ss.w + sdn.w) - m3);

    int deg = min(cnt[n], CAP);
    float4 w = make_float4(0.f, 0.f, 0.f, 0.f);
    int d = 0;
    if (lane < deg) {
        d = (int)bucket16[(size_t)n * CAP + lane];
        float4 sd = *(const float4*)&sdst4[(size_t)d * 4];
        w.x = __expf(lk(ss.x + sd.x) - m0);
        w.y = __expf(lk(ss.y + sd.y) - m1);
        w.z = __expf(lk(ss.z + sd.z) - m2);
        w.w = __expf(lk(ss.w + sd.w) - m3);
    }
    dsh[wv][lane] = d;                          // 0 for padded slots
    *(float4*)&wsh[wv][lane][0] = w;            // 0-weight for padded slots

    // denominators: butterfly reduce the per-lane w's (removes 4 FMA/slot from inner loop)
    float dn0 = w.x, dn1 = w.y, dn2 = w.z, dn3 = w.w;
#pragma unroll
    for (int st = 1; st < 64; st <<= 1) {
        dn0 += __shfl_xor(dn0, st);
        dn1 += __shfl_xor(dn1, st);
        dn2 += __shfl_xor(dn2, st);
        dn3 += __shfl_xor(dn3, st);
    }

    // self loop init
    float a0[4], a1[4];
    {
        unsigned int v = xb2[(size_t)n * 64 + lane];
        union { unsigned int u; float f; } lo, hi;
        lo.u = v << 16;
        hi.u = v & 0xffff0000u;
        a0[0] = w0s * lo.f; a1[0] = w0s * hi.f;
        a0[1] = w1s * lo.f; a1[1] = w1s * hi.f;
        a0[2] = w2s * lo.f; a1[2] = w2s * hi.f;
        a0[3] = w3s * lo.f; a1[3] = w3s * hi.f;
    }

    // same-wave LDS write->read: program order, no barrier needed.
    // dst indices are wave-uniform: readfirstlane -> SGPR base -> SALU addressing.
    int degp = (deg + 7) & ~7;
    for (int i = 0; i < degp; i += 8) {
        int du[8];
#pragma unroll
        for (int u = 0; u < 8; u++)
            du[u] = __builtin_amdgcn_readfirstlane(dsh[wv][i + u]);
        unsigned int vu[8];
#pragma unroll
        for (int u = 0; u < 8; u++)
            vu[u] = xb2[(size_t)du[u] * 64 + lane];
#pragma unroll
        for (int u = 0; u < 8; u++) {
            float4 w4 = *(const float4*)&wsh[wv][i + u][0];
            union { unsigned int uu; float f; } lo, hi;
            lo.uu = vu[u] << 16;
            hi.uu = vu[u] & 0xffff0000u;
            a0[0] += w4.x * lo.f; a1[0] += w4.x * hi.f;
            a0[1] += w4.y * lo.f; a1[1] += w4.y * hi.f;
            a0[2] += w4.z * lo.f; a1[2] += w4.z * hi.f;
            a0[3] += w4.w * lo.f; a1[3] += w4.w * hi.f;
        }
    }

    float4 e4 = *(const float4*)&ew[(size_t)n * 4];
    float i0 = e4.x / (w0s + dn0 + EPSF);
    float i1 = e4.y / (w1s + dn1 + EPSF);
    float i2 = e4.z / (w2s + dn2 + EPSF);
    float i3 = e4.w / (w3s + dn3 + EPSF);
    size_t zb = (size_t)n * 256;
    z2[zb +   0 + lane] = packbf(a0[0] * i0, a1[0] * i0);
    z2[zb +  64 + lane] = packbf(a0[1] * i1, a1[1] * i1);
    z2[zb + 128 + lane] = packbf(a0[2] * i2, a1[2] * i2);
    z2[zb + 192 + lane] = packbf(a0[3] * i3, a1[3] * i3);
}

// ---------------- gemm2: out = x + z (50000x512 bf16) @ Wcat (512x128 bf16) ----------------
#define MT 64
__global__ __launch_bounds__(256) void gemm2_kernel(const ushort* __restrict__ z,
                                                    const ushort* __restrict__ wt,
                                                    const float* __restrict__ x,
                                                    float* __restrict__ out) {
    int row0 = blockIdx.x * MT;
    int tid = threadIdx.x;
    int wave = tid >> 6, lane = tid & 63;
    int quad = lane >> 4, l16 = lane & 15;
    __shared__ ushort ws[F][136];

    int arow = row0 + wave * 16 + l16;
    if (arow >= NN) arow = NN - 1;

    f32x4 acc[8];
#pragma unroll
    for (int i = 0; i < 8; i++) acc[i] = (f32x4){0.f, 0.f, 0.f, 0.f};

    for (int k = 0; k < KH; k++) {
        __syncthreads();
        const ushort* wk = wt + (size_t)k * F * F;
        for (int i = tid; i < F * 16; i += 256) {
            int r = i >> 4, c = (i & 15) * 8;
            *(uint4*)&ws[r][c] = *(const uint4*)&wk[r * F + c];
        }
        __syncthreads();
#pragma unroll
        for (int kt = 0; kt < 4; kt++) {
            int kb = kt * 32 + quad * 8;
            bf16x8 af = *(const bf16x8*)&z[(size_t)arow * 512 + k * F + kb];
#pragma unroll
            for (int ni = 0; ni < 8; ni++) {
                bf16x8 bf = *(const bf16x8*)&ws[ni * 16 + l16][kb];
                acc[ni] = __builtin_amdgcn_mfma_f32_16x16x32_bf16(af, bf, acc[ni], 0, 0, 0);
            }
        }
    }
    // C/D: col = lane&15 (o-tile), row = quad*4 + reg (node)
#pragma unroll
    for (int r = 0; r < 4; r++) {
        int n = row0 + wave * 16 + quad * 4 + r;
        if (n < NN) {
#pragma unroll
            for (int ni = 0; ni < 8; ni++) {
                int o = ni * 16 + l16;
                out[(size_t)n * F + o] = x[(size_t)n * F + o] + acc[ni][r];
            }
        }
    }
}

extern "C" void kernel_launch(void* const* d_in, const int* in_sizes, int n_in,
                              void* d_out, int out_size, void* d_ws, size_t ws_size,
                              hipStream_t stream) {
    const float* x = (const float*)d_in[0];   // (50000,128)
    const float* e = (const float*)d_in[1];   // (50000,4)
    const float* W = (const float*)d_in[2];   // (4,128,128)
    const float* a = (const float*)d_in[3];   // (4,256,1)
    const int*   adj = (const int*)d_in[4];   // (2,1000000)
    float* out = (float*)d_out;

    char* ws = (char*)d_ws;
    auto take = [&](size_t bytes) {
        char* p = ws;
        ws += (bytes + 255) & ~(size_t)255;
        return p;
    };
    ushort* z      = (ushort*)take((size_t)NN * KH * F * sizeof(ushort)); // 51.2 MB, [n][k*F+o]
    unsigned int* xb2 = (unsigned int*)take((size_t)NN * F * sizeof(ushort)); // 12.8 MB bf16 x
    ushort* wt     = (ushort*)take((size_t)KH * F * F * sizeof(ushort));  // 128 KB
    float* ssrc4   = (float*)take((size_t)NN * 4 * sizeof(float));
    float* sdst4   = (float*)take((size_t)NN * 4 * sizeof(float));
    int*   cnt     = (int*)take((size_t)NBIN * 256 * sizeof(int));        // 200 KB (fully written by build)
    ushort* bucket16 = (ushort*)take((size_t)NBIN * 256 * CAP * sizeof(ushort)); // 6.4 MB
    unsigned int* binbuf = (unsigned int*)take((size_t)NBIN * BINCAP * sizeof(unsigned int)); // 6.4 MB
    int*   binTail = (int*)take((size_t)NBIN * TSTR * sizeof(int));       // 25 KB, line-padded
    float* mxs     = (float*)take((size_t)8 * MXSTR * sizeof(float));     // 8 maxima, 128 B apart
    float* vvg     = (float*)take((size_t)8 * F * sizeof(float));         // 4 KB

    vv_kernel<<<1, 256, 0, stream>>>(W, a, vvg, binTail, mxs);
    bin_prep_kernel<<<NB1 + NBP + NBW, 256, 0, stream>>>(adj, binTail, binbuf, W, wt,
                                                         vvg, x, xb2, ssrc4, sdst4, (int*)mxs);
    build_kernel<<<NBIN, 256, 0, stream>>>(binTail, binbuf, cnt, bucket16);
    aggregate_kernel<<<(NN + 3) / 4, 256, 0, stream>>>(xb2, ssrc4, sdst4, mxs, cnt,
                                                       bucket16, e, (unsigned int*)z);
    gemm2_kernel<<<(NN + MT - 1) / MT, 256, 0, stream>>>(z, wt, x, out);
}

// Round 15
// 215.454 us; speedup vs baseline: 1.0437x; 1.0437x over previous
//
#include <hip/hip_runtime.h>
#include <hip/hip_bf16.h>
#include <cstddef>

#define NN 50000
#define NE 1000000
#define F  128
#define KH 4
#define NEG 0.01f
#define EPSF 1e-8f
#define CAP 64
#define NBIN 196                       // bin = src >> 8  (50000>>8 = 195 max)
#define BINCAP 8192                    // mean 5102/bin, +43 sigma headroom
#define EPB 4096                       // edges per bin-block
#define NB1 ((NE + EPB - 1) / EPB)     // 245 edge-bin blocks
#define NBW 256                        // wt transpose blocks
#define NBP 2048                       // prep blocks (fused into K2)
#define STR (NBP * 4)                  // prep wave stride = 8192
#define MXSTR 32                       // mxs padding: 32 floats = 128 B/line

typedef short bf16x8 __attribute__((ext_vector_type(8)));
typedef float f32x4 __attribute__((ext_vector_type(4)));

__device__ inline ushort f2bf(float f) {
    __hip_bfloat16 b = __float2bfloat16(f);
    return *reinterpret_cast<ushort*>(&b);
}
__device__ inline unsigned int packbf(float xl, float xh) {
    return (unsigned int)f2bf(xl) | ((unsigned int)f2bf(xh) << 16);
}
__device__ inline float lk(float v) { return (v >= 0.f) ? v : NEG * v; }

// ---------------- K1: edge binning (multisplit) | W->bf16^T | vv precompute ----------------
__global__ __launch_bounds__(256) void bin_kernel(const int* __restrict__ adj,
                                                  int* __restrict__ binTail,
                                                  unsigned int* __restrict__ binbuf,
                                                  const float* __restrict__ W,
                                                  const float* __restrict__ a,
                                                  ushort* __restrict__ wt,
                                                  float* __restrict__ vvg) {
    int b = blockIdx.x;
    int tid = threadIdx.x;
    if (b < NB1) {
        // ---- bin edges by src>>8; one global fetch-add per (block,bin) ----
        __shared__ int hist[NBIN];
        __shared__ int rpos[NBIN];
        int base = b * EPB;
        int nloc = min(EPB, NE - base);
        for (int i = tid; i < NBIN; i += 256) hist[i] = 0;
        __syncthreads();
        unsigned int pk[16];
#pragma unroll
        for (int u = 0; u < 16; u++) {
            int off = u * 256 + tid;
            if (off < nloc) {
                int e = base + off;
                unsigned int s = (unsigned int)adj[e];
                unsigned int d = (unsigned int)adj[NE + e];
                pk[u] = (s << 16) | d;           // both < 65536
                atomicAdd(&hist[s >> 8], 1);
            } else pk[u] = 0xffffffffu;          // sentinel (s=65535 impossible)
        }
        __syncthreads();
        for (int i = tid; i < NBIN; i += 256) rpos[i] = atomicAdd(&binTail[i], hist[i]);
        __syncthreads();
#pragma unroll
        for (int u = 0; u < 16; u++) {
            if (pk[u] != 0xffffffffu) {
                int bn = pk[u] >> 24;
                int p = atomicAdd(&rpos[bn], 1);
                if (p < BINCAP) binbuf[(size_t)bn * BINCAP + p] = pk[u];
            }
        }
    } else if (b < NB1 + NBW) {
        // ---- W -> bf16 transposed: wt[k][o][d] ----
        int i = (b - NB1) * 256 + tid;           // covers KH*F*F = 65536
        int k = i >> 14;
        int dd = (i >> 7) & 127;
        int o = i & 127;
        wt[((size_t)k * F + o) * F + dd] = f2bf(W[i]);
    } else {
        // ---- vv: vvg[side*512 + k*128 + dd] = dot_o(W[k][dd][o], a[k][side*F+o]) ----
        int j0 = tid * 4;
#pragma unroll
        for (int ii = 0; ii < 4; ii++) {
            int j = j0 + ii;                      // 0..1023
            int side = j >> 9;
            int k = (j >> 7) & 3;
            int dd = j & 127;
            const float4* Wr = (const float4*)(W + (size_t)k * F * F + (size_t)dd * F);
            const float4* ar = (const float4*)(a + (size_t)k * 2 * F + side * F);
            float acc = 0.f;
#pragma unroll 8
            for (int o = 0; o < F / 4; o++) {
                float4 wv = Wr[o], av = ar[o];
                acc += wv.x * av.x + wv.y * av.y + wv.z * av.z + wv.w * av.w;
            }
            vvg[j] = acc;
        }
    }
}

// ---------------- K2: bucket build (2-pass, 2KB LDS) | prep (block-reduced maxima) ----------------
__global__ __launch_bounds__(256) void build_prep_kernel(const int* __restrict__ binTail,
                                                         const unsigned int* __restrict__ binbuf,
                                                         int* __restrict__ cnt,
                                                         ushort* __restrict__ bucket16,
                                                         const float* __restrict__ vvg,
                                                         const float* __restrict__ x,
                                                         unsigned int* __restrict__ xb2,
                                                         float* __restrict__ ssrc4,
                                                         float* __restrict__ sdst4,
                                                         int* __restrict__ mxsi) {
    int tid = threadIdx.x;
    __shared__ __align__(16) int shmem[1024];         // 4 KB, shared by both roles
    __shared__ float bmax_s[4][8];                     // per-wave maxima for block reduce

    if (blockIdx.x < NBIN) {
        // ---- bucket build: bin b covers nodes [b*256, b*256+256), two-pass, LDS = 2KB ----
        int b = blockIdx.x;
        int* lcnt = shmem;
        int* lpos = shmem + 256;
        lcnt[tid] = 0;
        lpos[tid] = 0;
        __syncthreads();
        int tail = min(binTail[b], BINCAP);
        const unsigned int* bb = binbuf + (size_t)b * BINCAP;
        for (int i = tid; i < tail; i += 256) {
            unsigned int pk = bb[i];
            atomicAdd(&lcnt[(pk >> 16) & 255], 1);
        }
        __syncthreads();
        int n0 = b << 8;
        cnt[n0 + tid] = lcnt[tid];
        for (int i = tid; i < tail; i += 256) {
            unsigned int pk = bb[i];                   // L2-hit re-read
            int sl = (pk >> 16) & 255;
            int p = atomicAdd(&lpos[sl], 1);
            if (p < CAP) bucket16[(size_t)(n0 + sl) * CAP + p] = (ushort)(pk & 0xffffu);
        }
        return;
    }

    // ---- prep ----
    float* vvf = (float*)shmem;                        // 8*128 floats
    ((float4*)vvf)[tid] = ((const float4*)vvg)[tid];   // 1024 floats
    __syncthreads();

    int wv = tid >> 6, lane = tid & 63;
    int gw = (blockIdx.x - NBIN) * 4 + wv;             // 0..8191
    const float2* x2 = (const float2*)x;
    float2 vs[4], vd[4];
#pragma unroll
    for (int k = 0; k < 4; k++) {
        vs[k] = *(const float2*)&vvf[k * F + 2 * lane];
        vd[k] = *(const float2*)&vvf[(4 + k) * F + 2 * lane];
    }
    int l1 = lane & 1, l2 = lane & 2, l4 = lane & 4;
    int j = 4 * l1 + l2 + (l4 >> 2);           // value index this lane ends with
    float* sp = (j < 4) ? (ssrc4 + j) : (sdst4 + (j - 4));
    float mxv = 0.f;

    for (int n = gw; n < NN; n += 2 * STR) {
        int nb = n + STR;
        bool vb = nb < NN;
        float2 xa = x2[(size_t)n * 64 + lane];
        float2 xbv = vb ? x2[(size_t)nb * 64 + lane] : make_float2(0.f, 0.f);
        xb2[(size_t)n * 64 + lane] = packbf(xa.x, xa.y);
        if (vb) xb2[(size_t)nb * 64 + lane] = packbf(xbv.x, xbv.y);
        float s[8], q[8];
#pragma unroll
        for (int k = 0; k < 4; k++) {
            s[k]     = xa.x * vs[k].x + xa.y * vs[k].y;
            s[4 + k] = xa.x * vd[k].x + xa.y * vd[k].y;
            q[k]     = xbv.x * vs[k].x + xbv.y * vs[k].y;
            q[4 + k] = xbv.x * vd[k].x + xbv.y * vd[k].y;
        }
        // two interleaved fold reduces: 8 values x 64 lanes -> per-lane totals
        float tA[4], tB[4];
#pragma unroll
        for (int i = 0; i < 4; i++) {
            float mA = l1 ? s[4 + i] : s[i];
            float oA = __shfl_xor(l1 ? s[i] : s[4 + i], 1);
            tA[i] = mA + oA;
            float mB = l1 ? q[4 + i] : q[i];
            float oB = __shfl_xor(l1 ? q[i] : q[4 + i], 1);
            tB[i] = mB + oB;
        }
        float uA[2], uB[2];
#pragma unroll
        for (int i = 0; i < 2; i++) {
            float mA = l2 ? tA[2 + i] : tA[i];
            float oA = __shfl_xor(l2 ? tA[i] : tA[2 + i], 2);
            uA[i] = mA + oA;
            float mB = l2 ? tB[2 + i] : tB[i];
            float oB = __shfl_xor(l2 ? tB[i] : tB[2 + i], 2);
            uB[i] = mB + oB;
        }
        float vA, vB;
        {
            float mA = l4 ? uA[1] : uA[0];
            float oA = __shfl_xor(l4 ? uA[0] : uA[1], 4);
            vA = mA + oA;
            float mB = l4 ? uB[1] : uB[0];
            float oB = __shfl_xor(l4 ? uB[0] : uB[1], 4);
            vB = mB + oB;
        }
        vA += __shfl_xor(vA, 8);  vB += __shfl_xor(vB, 8);
        vA += __shfl_xor(vA, 16); vB += __shfl_xor(vB, 16);
        vA += __shfl_xor(vA, 32); vB += __shfl_xor(vB, 32);
        if (lane < 8) {
            sp[(size_t)n * 4] = vA;
            if (vb) sp[(size_t)nb * 4] = vB;
        }
        mxv = fmaxf(mxv, fmaxf(vA, vB));   // vB == 0 when invalid: safe (max init 0)
    }
    // block-level max reduce -> 8 atomics per BLOCK, each on its own 128B line
    if (lane < 8) bmax_s[wv][j] = mxv;
    __syncthreads();
    if (tid < 8) {
        float m = fmaxf(fmaxf(bmax_s[0][tid], bmax_s[1][tid]),
                        fmaxf(bmax_s[2][tid], bmax_s[3][tid]));
        atomicMax(&mxsi[tid * MXSTR], __float_as_int(m));   // maxima >= 0: bit-monotone
    }
}

// ---------------- aggregate: wave-per-node, SALU-addressed gather, hoisted denominators ----------------
// z[n][k*F + o] = (e_k/(den_k+eps)) * (w_self*x[n] + sum_j w_jk * x[dst_j])   [bf16]
__global__ __launch_bounds__(256) void aggregate_kernel(const unsigned int* __restrict__ xb2,
                                                        const float* __restrict__ ssrc4,
                                                        const float* __restrict__ sdst4,
                                                        const float* __restrict__ mxs,
                                                        const int* __restrict__ cnt,
                                                        const ushort* __restrict__ bucket16,
                                                        const float* __restrict__ ew,
                                                        unsigned int* __restrict__ z2) {
    int wv = threadIdx.x >> 6, lane = threadIdx.x & 63;
    int n = blockIdx.x * 4 + wv;
    if (n >= NN) return;                       // wave-uniform; no barriers below

    __shared__ int dsh[4][64];
    __shared__ __align__(16) float wsh[4][64][4];

    float m0 = lk(mxs[0 * MXSTR] + mxs[4 * MXSTR]);
    float m1 = lk(mxs[1 * MXSTR] + mxs[5 * MXSTR]);
    float m2 = lk(mxs[2 * MXSTR] + mxs[6 * MXSTR]);
    float m3 = lk(mxs[3 * MXSTR] + mxs[7 * MXSTR]);
    float4 ss  = *(const float4*)&ssrc4[(size_t)n * 4];
    float4 sdn = *(const float4*)&sdst4[(size_t)n * 4];
    float w0s = __expf(lk(ss.x + sdn.x) - m0);
    float w1s = __expf(lk(ss.y + sdn.y) - m1);
    float w2s = __expf(lk(ss.z + sdn.z) - m2);
    float w3s = __expf(lk(ss.w + sdn.w) - m3);

    int deg = min(cnt[n], CAP);
    float4 w = make_float4(0.f, 0.f, 0.f, 0.f);
    int d = 0;
    if (lane < deg) {
        d = (int)bucket16[(size_t)n * CAP + lane];
        float4 sd = *(const float4*)&sdst4[(size_t)d * 4];
        w.x = __expf(lk(ss.x + sd.x) - m0);
        w.y = __expf(lk(ss.y + sd.y) - m1);
        w.z = __expf(lk(ss.z + sd.z) - m2);
        w.w = __expf(lk(ss.w + sd.w) - m3);
    }
    dsh[wv][lane] = d;                          // 0 for padded slots
    *(float4*)&wsh[wv][lane][0] = w;            // 0-weight for padded slots

    // denominators: butterfly reduce the per-lane w's (removes 4 FMA/slot from inner loop)
    float dn0 = w.x, dn1 = w.y, dn2 = w.z, dn3 = w.w;
#pragma unroll
    for (int st = 1; st < 64; st <<= 1) {
        dn0 += __shfl_xor(dn0, st);
        dn1 += __shfl_xor(dn1, st);
        dn2 += __shfl_xor(dn2, st);
        dn3 += __shfl_xor(dn3, st);
    }

    // self loop init
    float a0[4], a1[4];
    {
        unsigned int v = xb2[(size_t)n * 64 + lane];
        union { unsigned int u; float f; } lo, hi;
        lo.u = v << 16;
        hi.u = v & 0xffff0000u;
        a0[0] = w0s * lo.f; a1[0] = w0s * hi.f;
        a0[1] = w1s * lo.f; a1[1] = w1s * hi.f;
        a0[2] = w2s * lo.f; a1[2] = w2s * hi.f;
        a0[3] = w3s * lo.f; a1[3] = w3s * hi.f;
    }

    // same-wave LDS write->read: program order, no barrier needed.
    // dst indices are wave-uniform: readfirstlane -> SGPR base -> SALU addressing.
    int degp = (deg + 7) & ~7;
    for (int i = 0; i < degp; i += 8) {
        int du[8];
#pragma unroll
        for (int u = 0; u < 8; u++)
            du[u] = __builtin_amdgcn_readfirstlane(dsh[wv][i + u]);
        unsigned int vu[8];
#pragma unroll
        for (int u = 0; u < 8; u++)
            vu[u] = xb2[(size_t)du[u] * 64 + lane];
#pragma unroll
        for (int u = 0; u < 8; u++) {
            float4 w4 = *(const float4*)&wsh[wv][i + u][0];
            union { unsigned int uu; float f; } lo, hi;
            lo.uu = vu[u] << 16;
            hi.uu = vu[u] & 0xffff0000u;
            a0[0] += w4.x * lo.f; a1[0] += w4.x * hi.f;
            a0[1] += w4.y * lo.f; a1[1] += w4.y * hi.f;
            a0[2] += w4.z * lo.f; a1[2] += w4.z * hi.f;
            a0[3] += w4.w * lo.f; a1[3] += w4.w * hi.f;
        }
    }

    float4 e4 = *(const float4*)&ew[(size_t)n * 4];
    float i0 = e4.x / (w0s + dn0 + EPSF);
    float i1 = e4.y / (w1s + dn1 + EPSF);
    float i2 = e4.z / (w2s + dn2 + EPSF);
    float i3 = e4.w / (w3s + dn3 + EPSF);
    size_t zb = (size_t)n * 256;
    z2[zb +   0 + lane] = packbf(a0[0] * i0, a1[0] * i0);
    z2[zb +  64 + lane] = packbf(a0[1] * i1, a1[1] * i1);
    z2[zb + 128 + lane] = packbf(a0[2] * i2, a1[2] * i2);
    z2[zb + 192 + lane] = packbf(a0[3] * i3, a1[3] * i3);
}

// ---------------- gemm2: out = x + z (50000x512 bf16) @ Wcat (512x128 bf16) ----------------
#define MT 64
__global__ __launch_bounds__(256) void gemm2_kernel(const ushort* __restrict__ z,
                                                    const ushort* __restrict__ wt,
                                                    const float* __restrict__ x,
                                                    float* __restrict__ out) {
    int row0 = blockIdx.x * MT;
    int tid = threadIdx.x;
    int wave = tid >> 6, lane = tid & 63;
    int quad = lane >> 4, l16 = lane & 15;
    __shared__ ushort ws[F][136];

    int arow = row0 + wave * 16 + l16;
    if (arow >= NN) arow = NN - 1;

    f32x4 acc[8];
#pragma unroll
    for (int i = 0; i < 8; i++) acc[i] = (f32x4){0.f, 0.f, 0.f, 0.f};

    for (int k = 0; k < KH; k++) {
        __syncthreads();
        const ushort* wk = wt + (size_t)k * F * F;
        for (int i = tid; i < F * 16; i += 256) {
            int r = i >> 4, c = (i & 15) * 8;
            *(uint4*)&ws[r][c] = *(const uint4*)&wk[r * F + c];
        }
        __syncthreads();
#pragma unroll
        for (int kt = 0; kt < 4; kt++) {
            int kb = kt * 32 + quad * 8;
            bf16x8 af = *(const bf16x8*)&z[(size_t)arow * 512 + k * F + kb];
#pragma unroll
            for (int ni = 0; ni < 8; ni++) {
                bf16x8 bf = *(const bf16x8*)&ws[ni * 16 + l16][kb];
                acc[ni] = __builtin_amdgcn_mfma_f32_16x16x32_bf16(af, bf, acc[ni], 0, 0, 0);
            }
        }
    }
    // C/D: col = lane&15 (o-tile), row = quad*4 + reg (node)
#pragma unroll
    for (int r = 0; r < 4; r++) {
        int n = row0 + wave * 16 + quad * 4 + r;
        if (n < NN) {
#pragma unroll
            for (int ni = 0; ni < 8; ni++) {
                int o = ni * 16 + l16;
                out[(size_t)n * F + o] = x[(size_t)n * F + o] + acc[ni][r];
            }
        }
    }
}

extern "C" void kernel_launch(void* const* d_in, const int* in_sizes, int n_in,
                              void* d_out, int out_size, void* d_ws, size_t ws_size,
                              hipStream_t stream) {
    const float* x = (const float*)d_in[0];   // (50000,128)
    const float* e = (const float*)d_in[1];   // (50000,4)
    const float* W = (const float*)d_in[2];   // (4,128,128)
    const float* a = (const float*)d_in[3];   // (4,256,1)
    const int*   adj = (const int*)d_in[4];   // (2,1000000)
    float* out = (float*)d_out;

    char* ws = (char*)d_ws;
    auto take = [&](size_t bytes) {
        char* p = ws;
        ws += (bytes + 255) & ~(size_t)255;
        return p;
    };
    ushort* z      = (ushort*)take((size_t)NN * KH * F * sizeof(ushort)); // 51.2 MB, [n][k*F+o]
    unsigned int* xb2 = (unsigned int*)take((size_t)NN * F * sizeof(ushort)); // 12.8 MB bf16 x
    ushort* wt     = (ushort*)take((size_t)KH * F * F * sizeof(ushort));  // 128 KB
    float* ssrc4   = (float*)take((size_t)NN * 4 * sizeof(float));
    float* sdst4   = (float*)take((size_t)NN * 4 * sizeof(float));
    int*   cnt     = (int*)take((size_t)NBIN * 256 * sizeof(int));        // 200 KB (fully written by K2)
    ushort* bucket16 = (ushort*)take((size_t)NBIN * 256 * CAP * sizeof(ushort)); // 6.4 MB
    unsigned int* binbuf = (unsigned int*)take((size_t)NBIN * BINCAP * sizeof(unsigned int)); // 6.4 MB
    int*   binTail = (int*)take((size_t)NBIN * sizeof(int));              // 784 B
    float* mxs     = (float*)take((size_t)8 * MXSTR * sizeof(float));     // 8 maxima, 128 B apart
    float* vvg     = (float*)take((size_t)8 * F * sizeof(float));         // 4 KB

    hipMemsetAsync(binTail, 0, (size_t)NBIN * sizeof(int), stream);
    hipMemsetAsync(mxs, 0, (size_t)8 * MXSTR * sizeof(float), stream);
    bin_kernel<<<NB1 + NBW + 1, 256, 0, stream>>>(adj, binTail, binbuf, W, a, wt, vvg);
    build_prep_kernel<<<NBIN + NBP, 256, 0, stream>>>(binTail, binbuf, cnt, bucket16,
                                                      vvg, x, xb2, ssrc4, sdst4, (int*)mxs);
    aggregate_kernel<<<(NN + 3) / 4, 256, 0, stream>>>(xb2, ssrc4, sdst4, mxs, cnt,
                                                       bucket16, e, (unsigned int*)z);
    gemm2_kernel<<<(NN + MT - 1) / MT, 256, 0, stream>>>(z, wt, x, out);
}